// Round 13
// baseline (181.046 us; speedup 1.0000x reference)
//
#include <hip/hip_runtime.h>
#include <cstddef>

#define NB   32
#define CTXD 1024
#define FFD  8192
#define HD   256
#define WD   256
#define NPIX 65536
#define EPSF 1e-12f
#define SCF  4096.0f
#define ISCF (1.0f/4096.0f)

typedef __attribute__((ext_vector_type(8))) _Float16 half8;
typedef __attribute__((ext_vector_type(4))) float f32x4;

// ---------- helpers ----------

__device__ __forceinline__ float ftanh(float x){
  float ax = fabsf(x);
  float e  = __expf(2.0f*ax);
  float r  = 1.0f - 2.0f*__builtin_amdgcn_rcpf(e + 1.0f);
  return copysignf(r, x);
}

// split f32 -> 2 f16 terms: f ~= h0 + h1*2^-12 (residual ~2^-22 relative)
__device__ __forceinline__ void split2h(float f, _Float16& h0, _Float16& h1){
  h0 = (_Float16)f;
  float r = (f - (float)h0) * SCF;
  h1 = (_Float16)r;
}

// async global->LDS: lane L's 16B lands at l + L*16; global src per-lane
__device__ __forceinline__ void gload_lds16(const void* g, void* l){
  __builtin_amdgcn_global_load_lds(
      (__attribute__((address_space(1))) void*)g,
      (__attribute__((address_space(3))) void*)l, 16, 0, 0);
}

__device__ __forceinline__ void block_reduce4(float& a, float& b, float& c, float& d){
  for (int off = 32; off > 0; off >>= 1){
    a += __shfl_down(a, off); b += __shfl_down(b, off);
    c += __shfl_down(c, off); d += __shfl_down(d, off);
  }
  __shared__ float lds[16];
  int wid = threadIdx.x >> 6, lane = threadIdx.x & 63;
  if (lane == 0){ lds[wid*4+0]=a; lds[wid*4+1]=b; lds[wid*4+2]=c; lds[wid*4+3]=d; }
  __syncthreads();
  a = (lds[0]+lds[4])+(lds[8]+lds[12]);
  b = (lds[1]+lds[5])+(lds[9]+lds[13]);
  c = (lds[2]+lds[6])+(lds[10]+lds[14]);
  d = (lds[3]+lds[7])+(lds[11]+lds[15]);
}

// per-pixel recompute core shared by k_scan / k_final (must stay identical)
__device__ __forceinline__ void pixel_core(
    const float* __restrict__ lds, int h, int w, int pix,
    float cw0, float cw1, float cw2, float cw3, float cb,
    const float* __restrict__ wmod, const float* __restrict__ wstat,
    float& r_, float& i_, float& p_, float& q_){
  float sk[4];
  #pragma unroll
  for (int k = 0; k < 4; ++k){
    float acc = 0.f;
    #pragma unroll
    for (int r = 0; r < 4; ++r){
      int kr = k*4 + r;
      float u  = lds[kr*512 + h];
      float vv = lds[kr*512 + 256 + w];
      float tt = ftanh(u*vv);
      float cwr = (r==0)?cw0:(r==1)?cw1:(r==2)?cw2:cw3;
      acc += (k==0) ? cwr*tt : tt;
    }
    sk[k] = acc;
  }
  sk[0] += cb;
  float m0 = sk[0]*wmod[0*NPIX+pix];
  float m1 = sk[1]*wmod[1*NPIX+pix];
  float m2 = sk[2]*wmod[2*NPIX+pix];
  float m3 = sk[3]*wmod[3*NPIX+pix];
  float2 A1 = *(const float2*)(wstat + (size_t)(NPIX + pix)*2);
  r_ = A1.x*m0 - A1.y*m1;
  i_ = A1.x*m1 - A1.y*m0;
  p_ = m2; q_ = m3;
}

// ---------- kernels ----------

// split x [32][1024] f32 -> packed 2-plane f16 B-fragment layout, zero red[]
// pack per 32k chunk (2048 shorts): [plane2][half2][kg4][col16][8k]
__global__ __launch_bounds__(256) void k_prep(
    const float* __restrict__ x, unsigned short* __restrict__ P,
    float* __restrict__ red){
  int g = blockIdx.x*256 + threadIdx.x;      // 4096 = 32 rows x 128 groups
  if (g < 64) red[g] = 0.0f;
  int b = g >> 7, grp = g & 127;
  int c = grp >> 2, kg = grp & 3;
  const float* src = x + (size_t)b*CTXD + grp*8;
  float4 v0 = *(const float4*)(src), v1 = *(const float4*)(src+4);
  float vv[8] = {v0.x,v0.y,v0.z,v0.w,v1.x,v1.y,v1.z,v1.w};
  half8 g0, g1;
  #pragma unroll
  for (int e = 0; e < 8; ++e){
    _Float16 h0,h1; split2h(vv[e],h0,h1);
    g0[e]=h0; g1[e]=h1;
  }
  size_t base = (size_t)c*2048 + (b>>4)*512 + kg*128 + (b&15)*8;
  *(half8*)(P + base)        = g0;
  *(half8*)(P + base + 1024) = g1;
}

// B-reuse streaming 2xf16-split MFMA GEMM.
// Block = 4 waves x 128 features x kslice 256. B-pack slice (32KB) staged to
// LDS once; W staged per-step (128x32k, dbuf, per-wave-owned quarter).
// Two f32 accumulators: result = accH + accL/4096.
__global__ __launch_bounds__(256) void k_gemm_reuse(
    const float* __restrict__ W0, const float* __restrict__ W1,
    const unsigned short* __restrict__ BP,
    float* __restrict__ Cp, int K, size_t zstride){
  __shared__ float wtile[2][4096];           // 2 x (128 rows x 32 k) = 32KB
  __shared__ unsigned short bpack[16384];    // 8 chunks x 2048 = 32KB
  const int t = threadIdx.x;
  const int wv = t >> 6, lane = t & 63;
  const int row = lane & 15, kg = lane >> 4;
  const int f0 = blockIdx.x * 128;
  const int kc = blockIdx.y;
  const float* __restrict__ W = blockIdx.z ? W1 : W0;
  const int kb = kc * 256;

  // one-time B stage: 32 x 1KB calls, 8 per wave
  {
    const unsigned short* bsrc = BP + (size_t)(kc*8)*2048;
    #pragma unroll
    for (int i = 0; i < 8; ++i){
      int call = wv*8 + i;
      gload_lds16(bsrc + call*512 + lane*8, bpack + call*512);
    }
  }
  // W stage for step s into wtile[buf]; wave stages its 32 rows as 4 x 1KB
  // calls (8 rows x 128B). Source piece XOR-swizzled (T21).
  auto stageW = [&](int buf, int s){
    const int kbase = kb + s*32;
    #pragma unroll
    for (int i = 0; i < 4; ++i){
      int call = wv*4 + i;
      const float* src = W + (size_t)(f0 + call*8 + (lane>>3))*K + kbase
                           + (((lane&7) ^ ((lane>>3)&7)) << 2);
      gload_lds16(src, &wtile[buf][call*256]);
    }
  };

  stageW(0, 0);
  asm volatile("s_waitcnt vmcnt(0)" ::: "memory");
  __syncthreads();                            // B + first W tile visible

  f32x4 aH0l={0.f,0.f,0.f,0.f}, aH0h={0.f,0.f,0.f,0.f};
  f32x4 aL0l={0.f,0.f,0.f,0.f}, aL0h={0.f,0.f,0.f,0.f};
  f32x4 aH1l={0.f,0.f,0.f,0.f}, aH1h={0.f,0.f,0.f,0.f};
  f32x4 aL1l={0.f,0.f,0.f,0.f}, aL1h={0.f,0.f,0.f,0.f};
  int cur = 0;
  const int sw = row & 7;

  for (int s = 0; s < 8; ++s){
    if (s + 1 < 8) stageW(cur ^ 1, s + 1);
    asm volatile("s_waitcnt vmcnt(4)" ::: "memory");
    __builtin_amdgcn_sched_barrier(0);
    const unsigned short* bch = bpack + s*2048 + kg*128 + row*8;
    half8 b0l = *(const half8*)(bch);
    half8 b0h = *(const half8*)(bch +  512);
    half8 b1l = *(const half8*)(bch + 1024);
    half8 b1h = *(const half8*)(bch + 1536);
    #pragma unroll
    for (int T = 0; T < 2; ++T){
      const float* wr = &wtile[cur][(wv*32 + T*16 + row)*32];
      float4 lo = *(const float4*)(wr + (((2*kg  ) ^ sw) << 2));
      float4 hi = *(const float4*)(wr + (((2*kg+1) ^ sw) << 2));
      half8 a0, a1;
      float wv8[8] = {lo.x,lo.y,lo.z,lo.w,hi.x,hi.y,hi.z,hi.w};
      #pragma unroll
      for (int e = 0; e < 8; ++e){
        _Float16 h0,h1; split2h(wv8[e],h0,h1);
        a0[e]=h0; a1[e]=h1;
      }
      if (T == 0){
        aH0l = __builtin_amdgcn_mfma_f32_16x16x32_f16(a0, b0l, aH0l, 0,0,0);
        aH0h = __builtin_amdgcn_mfma_f32_16x16x32_f16(a0, b0h, aH0h, 0,0,0);
        aL0l = __builtin_amdgcn_mfma_f32_16x16x32_f16(a0, b1l, aL0l, 0,0,0);
        aL0h = __builtin_amdgcn_mfma_f32_16x16x32_f16(a0, b1h, aL0h, 0,0,0);
        aL0l = __builtin_amdgcn_mfma_f32_16x16x32_f16(a1, b0l, aL0l, 0,0,0);
        aL0h = __builtin_amdgcn_mfma_f32_16x16x32_f16(a1, b0h, aL0h, 0,0,0);
      } else {
        aH1l = __builtin_amdgcn_mfma_f32_16x16x32_f16(a0, b0l, aH1l, 0,0,0);
        aH1h = __builtin_amdgcn_mfma_f32_16x16x32_f16(a0, b0h, aH1h, 0,0,0);
        aL1l = __builtin_amdgcn_mfma_f32_16x16x32_f16(a0, b1l, aL1l, 0,0,0);
        aL1h = __builtin_amdgcn_mfma_f32_16x16x32_f16(a0, b1h, aL1h, 0,0,0);
        aL1l = __builtin_amdgcn_mfma_f32_16x16x32_f16(a1, b0l, aL1l, 0,0,0);
        aL1h = __builtin_amdgcn_mfma_f32_16x16x32_f16(a1, b0h, aL1h, 0,0,0);
      }
    }
    cur ^= 1;
  }

  float* __restrict__ C = Cp + (size_t)blockIdx.z*zstride + (size_t)kc*(FFD*32);
  #pragma unroll
  for (int r = 0; r < 4; ++r){               // C/D: col=lane&15, row=kg*4+r
    int fA = f0 + wv*32 + kg*4 + r;
    int fB = fA + 16;
    C[(size_t)fA*32 + row]      = aH0l[r] + aL0l[r]*ISCF;
    C[(size_t)fA*32 + 16 + row] = aH0h[r] + aL0h[r]*ISCF;
    C[(size_t)fB*32 + row]      = aH1l[r] + aL1l[r]*ISCF;
    C[(size_t)fB*32 + 16 + row] = aH1h[r] + aL1h[r]*ISCF;
  }
}

// fused reduce(G1 partials)+norm2048+gate -> packed 2-plane f16 ctx
__global__ __launch_bounds__(256) void k_norm1(
    const float* __restrict__ Cp, const float* __restrict__ bin,
    const float* __restrict__ bg, unsigned short* __restrict__ P){
  int b = blockIdx.x >> 2, g4 = blockIdx.x & 3;
  int t = threadIdx.x;
  int f8 = g4*2048 + t*8;
  float vt[8], vg[8];
  float st=0.f, sst=0.f, sg=0.f, ssg=0.f;
  #pragma unroll
  for (int i = 0; i < 8; ++i){
    int f = f8 + i;
    float a = bin[f], c = bg[f];
    #pragma unroll
    for (int kc = 0; kc < 4; ++kc){
      a += Cp[((size_t)kc*FFD + f)*32 + b];
      c += Cp[((size_t)(4+kc)*FFD + f)*32 + b];
    }
    vt[i]=a; vg[i]=c;
    st += a; sst += a*a; sg += c; ssg += c*c;
  }
  block_reduce4(st, sst, sg, ssg);
  float mt = st * (1.0f/2048.0f);
  float it = rsqrtf((sst - st*mt) * (1.0f/2047.0f) + EPSF);
  float mg = sg * (1.0f/2048.0f);
  float ig = rsqrtf((ssg - sg*mg) * (1.0f/2047.0f) + EPSF);
  half8 g0, g1;
  #pragma unroll
  for (int i = 0; i < 8; ++i){
    float nt = (vt[i]-mt)*it;
    float ng = (vg[i]-mg)*ig;
    float cv = nt * ftanh(ng);
    _Float16 h0,h1; split2h(cv,h0,h1);
    g0[i]=h0; g1[i]=h1;
  }
  int c2 = f8 >> 5, kg = (f8 >> 3) & 3;
  size_t base = (size_t)c2*2048 + (b>>4)*512 + kg*128 + (b&15)*8;
  *(half8*)(P + base)        = g0;
  *(half8*)(P + base + 1024) = g1;
}

// fused reduce(G2 partials, S=32)+norm512 -> modc [B][16][512]
__global__ __launch_bounds__(256) void k_norm2(
    const float* __restrict__ Cp, const float* __restrict__ bt,
    float* __restrict__ modc){
  int b = blockIdx.x >> 4, kr = blockIdx.x & 15;
  int t = threadIdx.x;
  int base = kr*512;
  int fa = base + t, fb = base + 256 + t;
  float v0 = bt[fa], v1 = bt[fb];
  #pragma unroll
  for (int s = 0; s < 32; ++s){
    v0 += Cp[((size_t)s*FFD + fa)*32 + b];
    v1 += Cp[((size_t)s*FFD + fb)*32 + b];
  }
  float s = v0+v1, ss = v0*v0 + v1*v1, d0=0.f, d1=0.f;
  block_reduce4(s, ss, d0, d1);
  float m   = s * (1.0f/512.0f);
  float inv = rsqrtf((ss - s*m) * (1.0f/511.0f) + EPSF);
  modc[b*FFD + fa] = (v0-m)*inv;
  modc[b*FFD + fb] = (v1-m)*inv;
}

// scan pass: per-batch max_s/max_p + Sigma|v_s| partials. No plane stores.
__global__ __launch_bounds__(256) void k_scan(
    const float* __restrict__ modc,
    const float* __restrict__ convw, const float* __restrict__ convb,
    const float* __restrict__ wmod, const float* __restrict__ wstat,
    float* __restrict__ red, float* __restrict__ magpart){
  int b = blockIdx.x >> 4, chunk = blockIdx.x & 15;
  int t = threadIdx.x;
  __shared__ float lds[16*512];
  #pragma unroll
  for (int i = 0; i < 8; ++i){
    float4 v = *(const float4*)(modc + (size_t)b*FFD + (i*256 + t)*4);
    *(float4*)(lds + (i*256 + t)*4) = v;
  }
  float cw0 = convw[0]+convw[4]+convw[8]+convw[12];
  float cw1 = convw[1]+convw[5]+convw[9]+convw[13];
  float cw2 = convw[2]+convw[6]+convw[10]+convw[14];
  float cw3 = convw[3]+convw[7]+convw[11]+convw[15];
  float cb  = convb[0]+convb[1]+convb[2]+convb[3];
  __syncthreads();
  int w = t;
  float mxs = 0.f, mxp = 0.f, sas = 0.f;
  for (int it = 0; it < 16; ++it){
    int h = chunk*16 + it;
    int pix = h*WD + w;
    float r_, i_, p_, q_;
    pixel_core(lds, h, w, pix, cw0, cw1, cw2, cw3, cb, wmod, wstat,
               r_, i_, p_, q_);
    float as = sqrtf(r_*r_ + i_*i_ + EPSF);
    float ap = sqrtf(p_*p_ + q_*q_ + EPSF);
    mxs = fmaxf(mxs, as); mxp = fmaxf(mxp, ap);
    sas += as;
  }
  for (int off = 32; off > 0; off >>= 1){
    mxs = fmaxf(mxs, __shfl_down(mxs, off));
    mxp = fmaxf(mxp, __shfl_down(mxp, off));
    sas += __shfl_down(sas, off);
  }
  __shared__ float lred[12];
  int wid = t >> 6, lane = t & 63;
  if (lane == 0){ lred[wid] = mxs; lred[4+wid] = mxp; lred[8+wid] = sas; }
  __syncthreads();
  if (t == 0){
    float a = fmaxf(fmaxf(lred[0],lred[1]), fmaxf(lred[2],lred[3]));
    float p = fmaxf(fmaxf(lred[4],lred[5]), fmaxf(lred[6],lred[7]));
    float s = (lred[8]+lred[9])+(lred[10]+lred[11]);
    atomicMax((int*)&red[b],    __float_as_int(a));
    atomicMax((int*)&red[32+b], __float_as_int(p));
    magpart[b*16 + chunk] = s;
  }
}

// final: recompute pixels, combine with per-batch stats -> out
__global__ __launch_bounds__(256) void k_final(
    const float* __restrict__ modc,
    const float* __restrict__ convw, const float* __restrict__ convb,
    const float* __restrict__ wmod, const float* __restrict__ wstat,
    const float* __restrict__ red, const float* __restrict__ magpart,
    float* __restrict__ out){
  int b = blockIdx.x >> 4, chunk = blockIdx.x & 15;
  int t = threadIdx.x;
  __shared__ float lds[16*512];
  __shared__ float s_im;
  if (t < 16){
    float v = magpart[b*16 + t];
    for (int off = 8; off > 0; off >>= 1) v += __shfl_down(v, off);
    if (t == 0){
      float maxs = red[b];
      s_im = rsqrtf(v*(1.0f/65536.0f)/(maxs + EPSF) + EPSF);
    }
  }
  #pragma unroll
  for (int i = 0; i < 8; ++i){
    float4 v = *(const float4*)(modc + (size_t)b*FFD + (i*256 + t)*4);
    *(float4*)(lds + (i*256 + t)*4) = v;
  }
  float cw0 = convw[0]+convw[4]+convw[8]+convw[12];
  float cw1 = convw[1]+convw[5]+convw[9]+convw[13];
  float cw2 = convw[2]+convw[6]+convw[10]+convw[14];
  float cw3 = convw[3]+convw[7]+convw[11]+convw[15];
  float cb  = convb[0]+convb[1]+convb[2]+convb[3];
  __syncthreads();
  float im = s_im;
  float maxs = red[b], maxp = red[32+b];
  int w = t;
  for (int it = 0; it < 16; ++it){
    int h = chunk*16 + it;
    int pix = h*WD + w;
    float r_, i_, p_, q_;
    pixel_core(lds, h, w, pix, cw0, cw1, cw2, cw3, cb, wmod, wstat,
               r_, i_, p_, q_);
    float as = sqrtf(r_*r_ + i_*i_ + EPSF);
    float fs = (as/(maxs+EPSF))/(as+EPSF)*im;
    float2 A0 = *(const float2*)(wstat + (size_t)pix*2);
    float mwr = A0.x + fs*r_;
    float mwi = A0.y + fs*i_;
    float ap = sqrtf(p_*p_ + q_*q_ + EPSF);
    float fp = (ap/(maxp+EPSF))/(ap+EPSF);
    float mpr = fp*p_, mpi = fp*q_;
    float den = sqrtf(mpr*mpr + mpi*mpi + EPSF);
    out[(size_t)b*NPIX + pix] = (mwr*mpr + mwi*mpi)/den;
  }
}

// ---------- launch ----------

extern "C" void kernel_launch(void* const* d_in, const int* in_sizes, int n_in,
                              void* d_out, int out_size, void* d_ws, size_t ws_size,
                              hipStream_t stream){
  const float* x     = (const float*)d_in[0];
  const float* Win   = (const float*)d_in[1];
  const float* bin   = (const float*)d_in[2];
  const float* Wg    = (const float*)d_in[3];
  const float* bg    = (const float*)d_in[4];
  const float* Wt    = (const float*)d_in[5];
  const float* bt    = (const float*)d_in[6];
  const float* convw = (const float*)d_in[7];
  const float* convb = (const float*)d_in[8];
  const float* wstat = (const float*)d_in[9];
  const float* wmod  = (const float*)d_in[10];
  float* out = (float*)d_out;
  float* ws  = (float*)d_ws;

  float* modc  = ws + 262144;              // [B][16][512]
  unsigned short* P2 = (unsigned short*)(ws + 524288);   // ctx pack, 256 chunks x 2048
  unsigned short* P1 = (unsigned short*)(ws + 917504);   // x pack, 32 chunks x 2048
  float* Cp    = ws + 966656;              // up to 32 x FFD*32 = 8.39M floats
  float* red     = ws + 9355264;           // max_s[32], max_p[32]
  float* magpart = ws + 9355328;           // [32][16]

  k_prep<<<16, 256, 0, stream>>>(x, P1, red);
  // GEMM1: K=1024, grid (f=64, kc=4, z=2), kslice=256
  k_gemm_reuse<<<dim3(64,4,2), 256, 0, stream>>>(Win, Wg, P1,
                                                 Cp, CTXD, 4ull*FFD*32);
  k_norm1<<<128, 256, 0, stream>>>(Cp, bin, bg, P2);
  // GEMM2: K=8192, grid (f=64, kc=32), kslice=256
  k_gemm_reuse<<<dim3(64,32,1), 256, 0, stream>>>(Wt, Wt, P2,
                                                  Cp, FFD, 0);
  k_norm2<<<512, 256, 0, stream>>>(Cp, bt, modc);
  k_scan<<<512, 256, 0, stream>>>(modc, convw, convb, wmod, wstat, red, magpart);
  k_final<<<512, 256, 0, stream>>>(modc, convw, convb, wmod, wstat, red,
                                   magpart, out);
}

// Round 14
// 154.400 us; speedup vs baseline: 1.1726x; 1.1726x over previous
//
#include <hip/hip_runtime.h>
#include <cstddef>

#define NB   32
#define CTXD 1024
#define FFD  8192
#define HD   256
#define WD   256
#define NPIX 65536
#define EPSF 1e-12f
#define SCF  4096.0f
#define ISCF (1.0f/4096.0f)

typedef __attribute__((ext_vector_type(8))) _Float16 half8;
typedef __attribute__((ext_vector_type(4))) float f32x4;

// ---------- helpers ----------

__device__ __forceinline__ float ftanh(float x){
  float ax = fabsf(x);
  float e  = __expf(2.0f*ax);
  float r  = 1.0f - 2.0f*__builtin_amdgcn_rcpf(e + 1.0f);
  return copysignf(r, x);
}

// split f32 -> 2 f16 terms: f ~= h0 + h1*2^-12 (residual ~2^-22 relative)
__device__ __forceinline__ void split2h(float f, _Float16& h0, _Float16& h1){
  h0 = (_Float16)f;
  float r = (f - (float)h0) * SCF;
  h1 = (_Float16)r;
}

// async global->LDS: lane L's 16B lands at l + L*16; global src per-lane
__device__ __forceinline__ void gload_lds16(const void* g, void* l){
  __builtin_amdgcn_global_load_lds(
      (__attribute__((address_space(1))) void*)g,
      (__attribute__((address_space(3))) void*)l, 16, 0, 0);
}

__device__ __forceinline__ void block_reduce4(float& a, float& b, float& c, float& d){
  for (int off = 32; off > 0; off >>= 1){
    a += __shfl_down(a, off); b += __shfl_down(b, off);
    c += __shfl_down(c, off); d += __shfl_down(d, off);
  }
  __shared__ float lds[16];
  int wid = threadIdx.x >> 6, lane = threadIdx.x & 63;
  if (lane == 0){ lds[wid*4+0]=a; lds[wid*4+1]=b; lds[wid*4+2]=c; lds[wid*4+3]=d; }
  __syncthreads();
  a = (lds[0]+lds[4])+(lds[8]+lds[12]);
  b = (lds[1]+lds[5])+(lds[9]+lds[13]);
  c = (lds[2]+lds[6])+(lds[10]+lds[14]);
  d = (lds[3]+lds[7])+(lds[11]+lds[15]);
}

// per-pixel recompute core shared by k_scan / k_final (must stay identical)
__device__ __forceinline__ void pixel_core(
    const float* __restrict__ lds, int h, int w, int pix,
    float cw0, float cw1, float cw2, float cw3, float cb,
    const float* __restrict__ wmod, const float* __restrict__ wstat,
    float& r_, float& i_, float& p_, float& q_){
  float sk[4];
  #pragma unroll
  for (int k = 0; k < 4; ++k){
    float acc = 0.f;
    #pragma unroll
    for (int r = 0; r < 4; ++r){
      int kr = k*4 + r;
      float u  = lds[kr*512 + h];
      float vv = lds[kr*512 + 256 + w];
      float tt = ftanh(u*vv);
      float cwr = (r==0)?cw0:(r==1)?cw1:(r==2)?cw2:cw3;
      acc += (k==0) ? cwr*tt : tt;
    }
    sk[k] = acc;
  }
  sk[0] += cb;
  float m0 = sk[0]*wmod[0*NPIX+pix];
  float m1 = sk[1]*wmod[1*NPIX+pix];
  float m2 = sk[2]*wmod[2*NPIX+pix];
  float m3 = sk[3]*wmod[3*NPIX+pix];
  float2 A1 = *(const float2*)(wstat + (size_t)(NPIX + pix)*2);
  r_ = A1.x*m0 - A1.y*m1;
  i_ = A1.x*m1 - A1.y*m0;
  p_ = m2; q_ = m3;
}

// ---------- kernels ----------

// split x [32][1024] f32 -> packed 2-plane f16 B-fragment layout, zero red[]
// pack per 32k chunk (2048 shorts): [plane2][half2][kg4][col16][8k]
__global__ __launch_bounds__(256) void k_prep(
    const float* __restrict__ x, unsigned short* __restrict__ P,
    float* __restrict__ red){
  int g = blockIdx.x*256 + threadIdx.x;      // 4096 = 32 rows x 128 groups
  if (g < 64) red[g] = 0.0f;
  int b = g >> 7, grp = g & 127;
  int c = grp >> 2, kg = grp & 3;
  const float* src = x + (size_t)b*CTXD + grp*8;
  float4 v0 = *(const float4*)(src), v1 = *(const float4*)(src+4);
  float vv[8] = {v0.x,v0.y,v0.z,v0.w,v1.x,v1.y,v1.z,v1.w};
  half8 g0, g1;
  #pragma unroll
  for (int e = 0; e < 8; ++e){
    _Float16 h0,h1; split2h(vv[e],h0,h1);
    g0[e]=h0; g1[e]=h1;
  }
  size_t base = (size_t)c*2048 + (b>>4)*512 + kg*128 + (b&15)*8;
  *(half8*)(P + base)        = g0;
  *(half8*)(P + base + 1024) = g1;
}

// B-reuse streaming 2xf16-split MFMA GEMM (r12 skeleton, split2 inner math).
// Block = 4 waves x 128 features x kslice 256. B-pack slice (32KB) staged to
// LDS once; W staged per-step (128x32k, dbuf, per-wave-owned quarter ->
// no in-loop barriers). Each wave computes 2 row-tiles reusing B fragments.
// result = accH + accL/4096. Cp[z][kc][f][b] partials.
__global__ __launch_bounds__(256) void k_gemm_reuse(
    const float* __restrict__ W0, const float* __restrict__ W1,
    const unsigned short* __restrict__ BP,
    float* __restrict__ Cp, int K, size_t zstride){
  __shared__ float wtile[2][4096];           // 2 x (128 rows x 32 k) = 32KB
  __shared__ unsigned short bpack[16384];    // 8 chunks x 2048 = 32KB
  const int t = threadIdx.x;
  const int wv = t >> 6, lane = t & 63;
  const int row = lane & 15, kg = lane >> 4;
  const int f0 = blockIdx.x * 128;
  const int kc = blockIdx.y;
  const float* __restrict__ W = blockIdx.z ? W1 : W0;
  const int kb = kc * 256;

  // one-time B stage: 32 x 1KB calls, 8 per wave
  {
    const unsigned short* bsrc = BP + (size_t)(kc*8)*2048;
    #pragma unroll
    for (int i = 0; i < 8; ++i){
      int call = wv*8 + i;
      gload_lds16(bsrc + call*512 + lane*8, bpack + call*512);
    }
  }
  // W stage for step s into wtile[buf]; wave stages its own 32 rows as
  // 4 x 1KB calls (8 rows x 128B each). Source piece XOR-swizzled (T21).
  auto stageW = [&](int buf, int s){
    const int kbase = kb + s*32;
    #pragma unroll
    for (int i = 0; i < 4; ++i){
      int call = wv*4 + i;
      const float* src = W + (size_t)(f0 + call*8 + (lane>>3))*K + kbase
                           + (((lane&7) ^ ((lane>>3)&7)) << 2);
      gload_lds16(src, &wtile[buf][call*256]);
    }
  };

  stageW(0, 0);
  asm volatile("s_waitcnt vmcnt(0)" ::: "memory");
  __syncthreads();                            // B + first W tile visible

  f32x4 aH0l={0.f,0.f,0.f,0.f}, aH0h={0.f,0.f,0.f,0.f};
  f32x4 aL0l={0.f,0.f,0.f,0.f}, aL0h={0.f,0.f,0.f,0.f};
  f32x4 aH1l={0.f,0.f,0.f,0.f}, aH1h={0.f,0.f,0.f,0.f};
  f32x4 aL1l={0.f,0.f,0.f,0.f}, aL1h={0.f,0.f,0.f,0.f};
  int cur = 0;
  const int sw = row & 7;

  for (int s = 0; s < 8; ++s){
    if (s + 1 < 8) stageW(cur ^ 1, s + 1);
    asm volatile("s_waitcnt vmcnt(4)" ::: "memory");
    __builtin_amdgcn_sched_barrier(0);
    // B fragments for this chunk (LDS, shared across both row-tiles)
    const unsigned short* bch = bpack + s*2048 + kg*128 + row*8;
    half8 b0l = *(const half8*)(bch);          // plane0, batches 0..15
    half8 b0h = *(const half8*)(bch +  512);   // plane0, batches 16..31
    half8 b1l = *(const half8*)(bch + 1024);   // plane1 (x4096)
    half8 b1h = *(const half8*)(bch + 1536);
    #pragma unroll
    for (int T = 0; T < 2; ++T){
      const float* wr = &wtile[cur][(wv*32 + T*16 + row)*32];
      float4 lo = *(const float4*)(wr + (((2*kg  ) ^ sw) << 2));
      float4 hi = *(const float4*)(wr + (((2*kg+1) ^ sw) << 2));
      half8 a0, a1;
      float wv8[8] = {lo.x,lo.y,lo.z,lo.w,hi.x,hi.y,hi.z,hi.w};
      #pragma unroll
      for (int e = 0; e < 8; ++e){
        _Float16 h0,h1; split2h(wv8[e],h0,h1);
        a0[e]=h0; a1[e]=h1;
      }
      if (T == 0){
        aH0l = __builtin_amdgcn_mfma_f32_16x16x32_f16(a0, b0l, aH0l, 0,0,0);
        aH0h = __builtin_amdgcn_mfma_f32_16x16x32_f16(a0, b0h, aH0h, 0,0,0);
        aL0l = __builtin_amdgcn_mfma_f32_16x16x32_f16(a0, b1l, aL0l, 0,0,0);
        aL0h = __builtin_amdgcn_mfma_f32_16x16x32_f16(a0, b1h, aL0h, 0,0,0);
        aL0l = __builtin_amdgcn_mfma_f32_16x16x32_f16(a1, b0l, aL0l, 0,0,0);
        aL0h = __builtin_amdgcn_mfma_f32_16x16x32_f16(a1, b0h, aL0h, 0,0,0);
      } else {
        aH1l = __builtin_amdgcn_mfma_f32_16x16x32_f16(a0, b0l, aH1l, 0,0,0);
        aH1h = __builtin_amdgcn_mfma_f32_16x16x32_f16(a0, b0h, aH1h, 0,0,0);
        aL1l = __builtin_amdgcn_mfma_f32_16x16x32_f16(a0, b1l, aL1l, 0,0,0);
        aL1h = __builtin_amdgcn_mfma_f32_16x16x32_f16(a0, b1h, aL1h, 0,0,0);
        aL1l = __builtin_amdgcn_mfma_f32_16x16x32_f16(a1, b0l, aL1l, 0,0,0);
        aL1h = __builtin_amdgcn_mfma_f32_16x16x32_f16(a1, b0h, aL1h, 0,0,0);
      }
    }
    cur ^= 1;
  }

  float* __restrict__ C = Cp + (size_t)blockIdx.z*zstride + (size_t)kc*(FFD*32);
  #pragma unroll
  for (int r = 0; r < 4; ++r){               // C/D: col=lane&15, row=kg*4+r
    int fA = f0 + wv*32 + kg*4 + r;
    int fB = fA + 16;
    C[(size_t)fA*32 + row]      = aH0l[r] + aL0l[r]*ISCF;
    C[(size_t)fA*32 + 16 + row] = aH0h[r] + aL0h[r]*ISCF;
    C[(size_t)fB*32 + row]      = aH1l[r] + aL1l[r]*ISCF;
    C[(size_t)fB*32 + 16 + row] = aH1h[r] + aL1h[r]*ISCF;
  }
}

// reduce for GEMM1 (both matrices), S=4 — coalesced (g-contiguous)
__global__ __launch_bounds__(256) void k_reduce1(
    const float* __restrict__ Cp, const float* __restrict__ bin,
    const float* __restrict__ bg, float* __restrict__ xtT,
    float* __restrict__ xgT){
  int g = blockIdx.x*256 + threadIdx.x;          // 524288
  int m = g >> 18, idx = g & 262143;
  int f = idx >> 5;
  const float* __restrict__ cp = Cp + (size_t)m*(4ull*FFD*32);
  float s = (m ? bg : bin)[f];
  #pragma unroll
  for (int sI = 0; sI < 4; ++sI) s += cp[(size_t)sI*(FFD*32) + idx];
  (m ? xgT : xtT)[idx] = s;
}

// reduce for GEMM2, S=32 — coalesced (g-contiguous)
__global__ __launch_bounds__(256) void k_reduce2(
    const float* __restrict__ Cp, const float* __restrict__ bias,
    float* __restrict__ outT){
  int g = blockIdx.x*256 + threadIdx.x;          // 262144
  int f = g >> 5;
  float s = bias[f];
  #pragma unroll
  for (int sI = 0; sI < 32; ++sI) s += Cp[(size_t)sI*(FFD*32) + g];
  outT[g] = s;
}

// norm over 2048-groups (ddof=1); ctx = nt*tanh(ng) -> packed f16 2-plane
__global__ __launch_bounds__(256) void k_normgate(
    const float* __restrict__ xtT, const float* __restrict__ xgT,
    unsigned short* __restrict__ P){
  int b = blockIdx.x >> 2, g4 = blockIdx.x & 3;
  int t = threadIdx.x;
  int f8 = g4*2048 + t*8;
  float vt[8], vg[8];
  float st=0.f, sst=0.f, sg=0.f, ssg=0.f;
  #pragma unroll
  for (int i = 0; i < 8; ++i){
    int f = f8 + i;
    float a = xtT[(size_t)f*NB + b];
    float c = xgT[(size_t)f*NB + b];
    vt[i]=a; vg[i]=c;
    st += a; sst += a*a; sg += c; ssg += c*c;
  }
  block_reduce4(st, sst, sg, ssg);
  float mt = st * (1.0f/2048.0f);
  float it = rsqrtf((sst - st*mt) * (1.0f/2047.0f) + EPSF);
  float mg = sg * (1.0f/2048.0f);
  float ig = rsqrtf((ssg - sg*mg) * (1.0f/2047.0f) + EPSF);
  half8 g0, g1;
  #pragma unroll
  for (int i = 0; i < 8; ++i){
    float nt = (vt[i]-mt)*it;
    float ng = (vg[i]-mg)*ig;
    float cv = nt * ftanh(ng);
    _Float16 h0,h1; split2h(cv,h0,h1);
    g0[i]=h0; g1[i]=h1;
  }
  int c2 = f8 >> 5, kg = (f8 >> 3) & 3;
  size_t base = (size_t)c2*2048 + (b>>4)*512 + kg*128 + (b&15)*8;
  *(half8*)(P + base)        = g0;
  *(half8*)(P + base + 1024) = g1;
}

// norm over 512-groups (ddof=1) -> modc [B][16][512]
__global__ __launch_bounds__(256) void k_norm512(
    const float* __restrict__ ctx2T, float* __restrict__ modc){
  int b = blockIdx.x >> 4, kr = blockIdx.x & 15;
  int t = threadIdx.x;
  int base = kr*512;
  float v0 = ctx2T[(base + t      )*NB + b];
  float v1 = ctx2T[(base + 256 + t)*NB + b];
  float s = v0+v1, ss = v0*v0 + v1*v1, d0=0.f, d1=0.f;
  block_reduce4(s, ss, d0, d1);
  float m   = s * (1.0f/512.0f);
  float inv = rsqrtf((ss - s*m) * (1.0f/511.0f) + EPSF);
  modc[b*FFD + base + t      ] = (v0-m)*inv;
  modc[b*FFD + base + 256 + t] = (v1-m)*inv;
}

// scan pass: per-batch max_s/max_p + Sigma|v_s| partials. No plane stores.
__global__ __launch_bounds__(256) void k_scan(
    const float* __restrict__ modc,
    const float* __restrict__ convw, const float* __restrict__ convb,
    const float* __restrict__ wmod, const float* __restrict__ wstat,
    float* __restrict__ red, float* __restrict__ magpart){
  int b = blockIdx.x >> 4, chunk = blockIdx.x & 15;
  int t = threadIdx.x;
  __shared__ float lds[16*512];
  #pragma unroll
  for (int i = 0; i < 8; ++i){
    float4 v = *(const float4*)(modc + (size_t)b*FFD + (i*256 + t)*4);
    *(float4*)(lds + (i*256 + t)*4) = v;
  }
  float cw0 = convw[0]+convw[4]+convw[8]+convw[12];
  float cw1 = convw[1]+convw[5]+convw[9]+convw[13];
  float cw2 = convw[2]+convw[6]+convw[10]+convw[14];
  float cw3 = convw[3]+convw[7]+convw[11]+convw[15];
  float cb  = convb[0]+convb[1]+convb[2]+convb[3];
  __syncthreads();
  int w = t;
  float mxs = 0.f, mxp = 0.f, sas = 0.f;
  for (int it = 0; it < 16; ++it){
    int h = chunk*16 + it;
    int pix = h*WD + w;
    float r_, i_, p_, q_;
    pixel_core(lds, h, w, pix, cw0, cw1, cw2, cw3, cb, wmod, wstat,
               r_, i_, p_, q_);
    float as = sqrtf(r_*r_ + i_*i_ + EPSF);
    float ap = sqrtf(p_*p_ + q_*q_ + EPSF);
    mxs = fmaxf(mxs, as); mxp = fmaxf(mxp, ap);
    sas += as;
  }
  for (int off = 32; off > 0; off >>= 1){
    mxs = fmaxf(mxs, __shfl_down(mxs, off));
    mxp = fmaxf(mxp, __shfl_down(mxp, off));
    sas += __shfl_down(sas, off);
  }
  __shared__ float lred[12];
  int wid = t >> 6, lane = t & 63;
  if (lane == 0){ lred[wid] = mxs; lred[4+wid] = mxp; lred[8+wid] = sas; }
  __syncthreads();
  if (t == 0){
    float a = fmaxf(fmaxf(lred[0],lred[1]), fmaxf(lred[2],lred[3]));
    float p = fmaxf(fmaxf(lred[4],lred[5]), fmaxf(lred[6],lred[7]));
    float s = (lred[8]+lred[9])+(lred[10]+lred[11]);
    atomicMax((int*)&red[b],    __float_as_int(a));
    atomicMax((int*)&red[32+b], __float_as_int(p));
    magpart[b*16 + chunk] = s;
  }
}

// final: recompute pixels, combine with per-batch stats -> out
__global__ __launch_bounds__(256) void k_final(
    const float* __restrict__ modc,
    const float* __restrict__ convw, const float* __restrict__ convb,
    const float* __restrict__ wmod, const float* __restrict__ wstat,
    const float* __restrict__ red, const float* __restrict__ magpart,
    float* __restrict__ out){
  int b = blockIdx.x >> 4, chunk = blockIdx.x & 15;
  int t = threadIdx.x;
  __shared__ float lds[16*512];
  __shared__ float s_im;
  if (t < 16){
    float v = magpart[b*16 + t];
    for (int off = 8; off > 0; off >>= 1) v += __shfl_down(v, off);
    if (t == 0){
      float maxs = red[b];
      s_im = rsqrtf(v*(1.0f/65536.0f)/(maxs + EPSF) + EPSF);
    }
  }
  #pragma unroll
  for (int i = 0; i < 8; ++i){
    float4 v = *(const float4*)(modc + (size_t)b*FFD + (i*256 + t)*4);
    *(float4*)(lds + (i*256 + t)*4) = v;
  }
  float cw0 = convw[0]+convw[4]+convw[8]+convw[12];
  float cw1 = convw[1]+convw[5]+convw[9]+convw[13];
  float cw2 = convw[2]+convw[6]+convw[10]+convw[14];
  float cw3 = convw[3]+convw[7]+convw[11]+convw[15];
  float cb  = convb[0]+convb[1]+convb[2]+convb[3];
  __syncthreads();
  float im = s_im;
  float maxs = red[b], maxp = red[32+b];
  int w = t;
  for (int it = 0; it < 16; ++it){
    int h = chunk*16 + it;
    int pix = h*WD + w;
    float r_, i_, p_, q_;
    pixel_core(lds, h, w, pix, cw0, cw1, cw2, cw3, cb, wmod, wstat,
               r_, i_, p_, q_);
    float as = sqrtf(r_*r_ + i_*i_ + EPSF);
    float fs = (as/(maxs+EPSF))/(as+EPSF)*im;
    float2 A0 = *(const float2*)(wstat + (size_t)pix*2);
    float mwr = A0.x + fs*r_;
    float mwi = A0.y + fs*i_;
    float ap = sqrtf(p_*p_ + q_*q_ + EPSF);
    float fp = (ap/(maxp+EPSF))/(ap+EPSF);
    float mpr = fp*p_, mpi = fp*q_;
    float den = sqrtf(mpr*mpr + mpi*mpi + EPSF);
    out[(size_t)b*NPIX + pix] = (mwr*mpr + mwi*mpi)/den;
  }
}

// ---------- launch ----------

extern "C" void kernel_launch(void* const* d_in, const int* in_sizes, int n_in,
                              void* d_out, int out_size, void* d_ws, size_t ws_size,
                              hipStream_t stream){
  const float* x     = (const float*)d_in[0];
  const float* Win   = (const float*)d_in[1];
  const float* bin   = (const float*)d_in[2];
  const float* Wg    = (const float*)d_in[3];
  const float* bg    = (const float*)d_in[4];
  const float* Wt    = (const float*)d_in[5];
  const float* bt    = (const float*)d_in[6];
  const float* convw = (const float*)d_in[7];
  const float* convb = (const float*)d_in[8];
  const float* wstat = (const float*)d_in[9];
  const float* wmod  = (const float*)d_in[10];
  float* out = (float*)d_out;
  float* ws  = (float*)d_ws;

  // layout (floats); aliases are lifetime-disjoint:
  float* xtT   = ws;                       // dead after normgate
  float* xgT   = ws + 262144;              // dead after normgate
  float* ctx2T = ws;                       // alias xtT
  float* modc  = ws + 262144;              // alias xgT
  unsigned short* P2 = (unsigned short*)(ws + 524288);   // ctx pack, 256x2048 sh
  unsigned short* P1 = (unsigned short*)(ws + 917504);   // x pack, 32x2048 sh
  float* Cp    = ws + 966656;              // up to 32 x FFD*32 = 8.39M floats
  float* red     = ws + 9355264;           // max_s[32], max_p[32]
  float* magpart = ws + 9355328;           // [32][16]

  k_prep<<<16, 256, 0, stream>>>(x, P1, red);
  // GEMM1: K=1024, grid (f=64, kc=4, z=2), kslice=256
  k_gemm_reuse<<<dim3(64,4,2), 256, 0, stream>>>(Win, Wg, P1,
                                                 Cp, CTXD, 4ull*FFD*32);
  k_reduce1<<<2048, 256, 0, stream>>>(Cp, bin, bg, xtT, xgT);
  k_normgate<<<128, 256, 0, stream>>>(xtT, xgT, P2);
  // GEMM2: K=8192, grid (f=64, kc=32), kslice=256
  k_gemm_reuse<<<dim3(64,32,1), 256, 0, stream>>>(Wt, Wt, P2,
                                                  Cp, FFD, 0);
  k_reduce2<<<1024, 256, 0, stream>>>(Cp, bt, ctx2T);
  k_norm512<<<512, 256, 0, stream>>>(ctx2T, modc);
  k_scan<<<512, 256, 0, stream>>>(modc, convw, convb, wmod, wstat, red, magpart);
  k_final<<<512, 256, 0, stream>>>(modc, convw, convb, wmod, wstat, red,
                                   magpart, out);
}

// Round 15
// 152.249 us; speedup vs baseline: 1.1891x; 1.0141x over previous
//
#include <hip/hip_runtime.h>
#include <cstddef>

#define NB   32
#define CTXD 1024
#define FFD  8192
#define HD   256
#define WD   256
#define NPIX 65536
#define EPSF 1e-12f
#define SCF  4096.0f
#define ISCF (1.0f/4096.0f)

typedef __attribute__((ext_vector_type(8))) _Float16 half8;
typedef __attribute__((ext_vector_type(4))) float f32x4;

// ---------- helpers ----------

__device__ __forceinline__ float ftanh(float x){
  float ax = fabsf(x);
  float e  = __expf(2.0f*ax);
  float r  = 1.0f - 2.0f*__builtin_amdgcn_rcpf(e + 1.0f);
  return copysignf(r, x);
}

// split f32 -> 2 f16 terms: f ~= h0 + h1*2^-12 (residual ~2^-22 relative)
__device__ __forceinline__ void split2h(float f, _Float16& h0, _Float16& h1){
  h0 = (_Float16)f;
  float r = (f - (float)h0) * SCF;
  h1 = (_Float16)r;
}

// async global->LDS: lane L's 16B lands at l + L*16; global src per-lane
__device__ __forceinline__ void gload_lds16(const void* g, void* l){
  __builtin_amdgcn_global_load_lds(
      (__attribute__((address_space(1))) void*)g,
      (__attribute__((address_space(3))) void*)l, 16, 0, 0);
}

__device__ __forceinline__ void block_reduce4(float& a, float& b, float& c, float& d){
  for (int off = 32; off > 0; off >>= 1){
    a += __shfl_down(a, off); b += __shfl_down(b, off);
    c += __shfl_down(c, off); d += __shfl_down(d, off);
  }
  __shared__ float lds[16];
  int wid = threadIdx.x >> 6, lane = threadIdx.x & 63;
  if (lane == 0){ lds[wid*4+0]=a; lds[wid*4+1]=b; lds[wid*4+2]=c; lds[wid*4+3]=d; }
  __syncthreads();
  a = (lds[0]+lds[4])+(lds[8]+lds[12]);
  b = (lds[1]+lds[5])+(lds[9]+lds[13]);
  c = (lds[2]+lds[6])+(lds[10]+lds[14]);
  d = (lds[3]+lds[7])+(lds[11]+lds[15]);
}

// per-pixel recompute core shared by k_scan / k_final (must stay identical)
__device__ __forceinline__ void pixel_core(
    const float* __restrict__ lds, int h, int w, int pix,
    float cw0, float cw1, float cw2, float cw3, float cb,
    const float* __restrict__ wmod, const float* __restrict__ wstat,
    float& r_, float& i_, float& p_, float& q_){
  float sk[4];
  #pragma unroll
  for (int k = 0; k < 4; ++k){
    float acc = 0.f;
    #pragma unroll
    for (int r = 0; r < 4; ++r){
      int kr = k*4 + r;
      float u  = lds[kr*512 + h];
      float vv = lds[kr*512 + 256 + w];
      float tt = ftanh(u*vv);
      float cwr = (r==0)?cw0:(r==1)?cw1:(r==2)?cw2:cw3;
      acc += (k==0) ? cwr*tt : tt;
    }
    sk[k] = acc;
  }
  sk[0] += cb;
  float m0 = sk[0]*wmod[0*NPIX+pix];
  float m1 = sk[1]*wmod[1*NPIX+pix];
  float m2 = sk[2]*wmod[2*NPIX+pix];
  float m3 = sk[3]*wmod[3*NPIX+pix];
  float2 A1 = *(const float2*)(wstat + (size_t)(NPIX + pix)*2);
  r_ = A1.x*m0 - A1.y*m1;
  i_ = A1.x*m1 - A1.y*m0;
  p_ = m2; q_ = m3;
}

// ---------- kernels ----------

// B-reuse streaming 2xf16-split MFMA GEMM (r14 skeleton).
// Block = 4 waves x 128 features x kslice STEPS*32.
// PACKB=true  (GEMM1): B built in-kernel from f32 X slice (coalesced reads,
//                      ds_write pack); also zeroes red[] from block 0.
// PACKB=false (GEMM2): B staged from the packed ctx buffer in two 8-chunk
//                      halves (mid-loop restage at s==8).
// W staged per-step (128x32k, dbuf, per-wave-owned quarter, no in-loop
// barriers). result = accH + accL/4096. Cp[z][kc][f][b] partials.
template<int STEPS, bool PACKB>
__global__ __launch_bounds__(256) void k_gemm(
    const float* __restrict__ W0, const float* __restrict__ W1,
    const unsigned short* __restrict__ BP, const float* __restrict__ X,
    float* __restrict__ Cp, float* __restrict__ red, int K, size_t zstride){
  __shared__ float wtile[2][4096];           // 2 x (128 rows x 32 k) = 32KB
  __shared__ unsigned short bpack[16384];    // 8 chunks x 2048 = 32KB
  const int t = threadIdx.x;
  const int wv = t >> 6, lane = t & 63;
  const int row = lane & 15, kg = lane >> 4;
  const int f0 = blockIdx.x * 128;
  const int kc = blockIdx.y;
  const float* __restrict__ W = blockIdx.z ? W1 : W0;
  const int kb = kc * (STEPS*32);

  if (PACKB && blockIdx.x == 0 && blockIdx.y == 0 && blockIdx.z == 0 && t < 64)
    red[t] = 0.0f;

  if constexpr (PACKB){
    // build B pack from f32 X slice: 1024 units (32 b x 32 8k-groups)
    for (int u = t; u < 1024; u += 256){
      int b = u >> 5, grp = u & 31;
      const float* src = X + (size_t)b*K + kb + grp*8;
      float4 v0 = *(const float4*)(src), v1 = *(const float4*)(src+4);
      float vv[8] = {v0.x,v0.y,v0.z,v0.w,v1.x,v1.y,v1.z,v1.w};
      half8 g0, g1;
      #pragma unroll
      for (int e = 0; e < 8; ++e){
        _Float16 h0,h1; split2h(vv[e],h0,h1);
        g0[e]=h0; g1[e]=h1;
      }
      int c = grp >> 2, kgp = grp & 3;
      size_t base = (size_t)c*2048 + (b>>4)*512 + kgp*128 + (b&15)*8;
      *(half8*)(bpack + base)        = g0;
      *(half8*)(bpack + base + 1024) = g1;
    }
  } else {
    const unsigned short* bsrc = BP + (size_t)(kc*STEPS)*2048;
    #pragma unroll
    for (int i = 0; i < 8; ++i){
      int call = wv*8 + i;
      gload_lds16(bsrc + call*512 + lane*8, bpack + call*512);
    }
  }
  // W stage for step s into wtile[buf]; wave stages its own 32 rows as
  // 4 x 1KB calls (8 rows x 128B each). Source piece XOR-swizzled (T21).
  auto stageW = [&](int buf, int s){
    const int kbase = kb + s*32;
    #pragma unroll
    for (int i = 0; i < 4; ++i){
      int call = wv*4 + i;
      const float* src = W + (size_t)(f0 + call*8 + (lane>>3))*K + kbase
                           + (((lane&7) ^ ((lane>>3)&7)) << 2);
      gload_lds16(src, &wtile[buf][call*256]);
    }
  };

  stageW(0, 0);
  asm volatile("s_waitcnt vmcnt(0)" ::: "memory");
  __syncthreads();                            // B(+pack writes) + W0 visible

  f32x4 aH0l={0.f,0.f,0.f,0.f}, aH0h={0.f,0.f,0.f,0.f};
  f32x4 aL0l={0.f,0.f,0.f,0.f}, aL0h={0.f,0.f,0.f,0.f};
  f32x4 aH1l={0.f,0.f,0.f,0.f}, aH1h={0.f,0.f,0.f,0.f};
  f32x4 aL1l={0.f,0.f,0.f,0.f}, aL1h={0.f,0.f,0.f,0.f};
  int cur = 0;
  const int sw = row & 7;

  for (int s = 0; s < STEPS; ++s){
    if constexpr (STEPS > 8){
      if (s == 8){
        __syncthreads();                      // all waves done with chunks 0-7
        const unsigned short* bsrc = BP + (size_t)(kc*STEPS + 8)*2048;
        #pragma unroll
        for (int i = 0; i < 8; ++i){
          int call = wv*8 + i;
          gload_lds16(bsrc + call*512 + lane*8, bpack + call*512);
        }
      }
    }
    if (s + 1 < STEPS) stageW(cur ^ 1, s + 1);
    // wait: everything older than stage(s+1)'s 4 ops is drained
    asm volatile("s_waitcnt vmcnt(4)" ::: "memory");
    __builtin_amdgcn_sched_barrier(0);
    const unsigned short* bch = bpack + (size_t)(s & 7)*2048 + kg*128 + row*8;
    half8 b0l = *(const half8*)(bch);          // plane0, batches 0..15
    half8 b0h = *(const half8*)(bch +  512);   // plane0, batches 16..31
    half8 b1l = *(const half8*)(bch + 1024);   // plane1 (x4096)
    half8 b1h = *(const half8*)(bch + 1536);
    #pragma unroll
    for (int T = 0; T < 2; ++T){
      const float* wr = &wtile[cur][(wv*32 + T*16 + row)*32];
      float4 lo = *(const float4*)(wr + (((2*kg  ) ^ sw) << 2));
      float4 hi = *(const float4*)(wr + (((2*kg+1) ^ sw) << 2));
      half8 a0, a1;
      float wv8[8] = {lo.x,lo.y,lo.z,lo.w,hi.x,hi.y,hi.z,hi.w};
      #pragma unroll
      for (int e = 0; e < 8; ++e){
        _Float16 h0,h1; split2h(wv8[e],h0,h1);
        a0[e]=h0; a1[e]=h1;
      }
      if (T == 0){
        aH0l = __builtin_amdgcn_mfma_f32_16x16x32_f16(a0, b0l, aH0l, 0,0,0);
        aH0h = __builtin_amdgcn_mfma_f32_16x16x32_f16(a0, b0h, aH0h, 0,0,0);
        aL0l = __builtin_amdgcn_mfma_f32_16x16x32_f16(a0, b1l, aL0l, 0,0,0);
        aL0h = __builtin_amdgcn_mfma_f32_16x16x32_f16(a0, b1h, aL0h, 0,0,0);
        aL0l = __builtin_amdgcn_mfma_f32_16x16x32_f16(a1, b0l, aL0l, 0,0,0);
        aL0h = __builtin_amdgcn_mfma_f32_16x16x32_f16(a1, b0h, aL0h, 0,0,0);
      } else {
        aH1l = __builtin_amdgcn_mfma_f32_16x16x32_f16(a0, b0l, aH1l, 0,0,0);
        aH1h = __builtin_amdgcn_mfma_f32_16x16x32_f16(a0, b0h, aH1h, 0,0,0);
        aL1l = __builtin_amdgcn_mfma_f32_16x16x32_f16(a0, b1l, aL1l, 0,0,0);
        aL1h = __builtin_amdgcn_mfma_f32_16x16x32_f16(a0, b1h, aL1h, 0,0,0);
        aL1l = __builtin_amdgcn_mfma_f32_16x16x32_f16(a1, b0l, aL1l, 0,0,0);
        aL1h = __builtin_amdgcn_mfma_f32_16x16x32_f16(a1, b0h, aL1h, 0,0,0);
      }
    }
    cur ^= 1;
  }

  float* __restrict__ C = Cp + (size_t)blockIdx.z*zstride + (size_t)kc*(FFD*32);
  #pragma unroll
  for (int r = 0; r < 4; ++r){               // C/D: col=lane&15, row=kg*4+r
    int fA = f0 + wv*32 + kg*4 + r;
    int fB = fA + 16;
    C[(size_t)fA*32 + row]      = aH0l[r] + aL0l[r]*ISCF;
    C[(size_t)fA*32 + 16 + row] = aH0h[r] + aL0h[r]*ISCF;
    C[(size_t)fB*32 + row]      = aH1l[r] + aL1l[r]*ISCF;
    C[(size_t)fB*32 + 16 + row] = aH1h[r] + aL1h[r]*ISCF;
  }
}

// reduce for GEMM1 (both matrices), S=4 — coalesced (g-contiguous)
__global__ __launch_bounds__(256) void k_reduce1(
    const float* __restrict__ Cp, const float* __restrict__ bin,
    const float* __restrict__ bg, float* __restrict__ xtT,
    float* __restrict__ xgT){
  int g = blockIdx.x*256 + threadIdx.x;          // 524288
  int m = g >> 18, idx = g & 262143;
  int f = idx >> 5;
  const float* __restrict__ cp = Cp + (size_t)m*(4ull*FFD*32);
  float s = (m ? bg : bin)[f];
  #pragma unroll
  for (int sI = 0; sI < 4; ++sI) s += cp[(size_t)sI*(FFD*32) + idx];
  (m ? xgT : xtT)[idx] = s;
}

// reduce for GEMM2, S=16 — coalesced (g-contiguous)
__global__ __launch_bounds__(256) void k_reduce2(
    const float* __restrict__ Cp, const float* __restrict__ bias,
    float* __restrict__ outT){
  int g = blockIdx.x*256 + threadIdx.x;          // 262144
  int f = g >> 5;
  float s = bias[f];
  #pragma unroll
  for (int sI = 0; sI < 16; ++sI) s += Cp[(size_t)sI*(FFD*32) + g];
  outT[g] = s;
}

// norm over 2048-groups (ddof=1); ctx = nt*tanh(ng) -> packed f16 2-plane
__global__ __launch_bounds__(256) void k_normgate(
    const float* __restrict__ xtT, const float* __restrict__ xgT,
    unsigned short* __restrict__ P){
  int b = blockIdx.x >> 2, g4 = blockIdx.x & 3;
  int t = threadIdx.x;
  int f8 = g4*2048 + t*8;
  float vt[8], vg[8];
  float st=0.f, sst=0.f, sg=0.f, ssg=0.f;
  #pragma unroll
  for (int i = 0; i < 8; ++i){
    int f = f8 + i;
    float a = xtT[(size_t)f*NB + b];
    float c = xgT[(size_t)f*NB + b];
    vt[i]=a; vg[i]=c;
    st += a; sst += a*a; sg += c; ssg += c*c;
  }
  block_reduce4(st, sst, sg, ssg);
  float mt = st * (1.0f/2048.0f);
  float it = rsqrtf((sst - st*mt) * (1.0f/2047.0f) + EPSF);
  float mg = sg * (1.0f/2048.0f);
  float ig = rsqrtf((ssg - sg*mg) * (1.0f/2047.0f) + EPSF);
  half8 g0, g1;
  #pragma unroll
  for (int i = 0; i < 8; ++i){
    float nt = (vt[i]-mt)*it;
    float ng = (vg[i]-mg)*ig;
    float cv = nt * ftanh(ng);
    _Float16 h0,h1; split2h(cv,h0,h1);
    g0[i]=h0; g1[i]=h1;
  }
  int c2 = f8 >> 5, kg = (f8 >> 3) & 3;
  size_t base = (size_t)c2*2048 + (b>>4)*512 + kg*128 + (b&15)*8;
  *(half8*)(P + base)        = g0;
  *(half8*)(P + base + 1024) = g1;
}

// norm over 512-groups (ddof=1) -> modc [B][16][512]
__global__ __launch_bounds__(256) void k_norm512(
    const float* __restrict__ ctx2T, float* __restrict__ modc){
  int b = blockIdx.x >> 4, kr = blockIdx.x & 15;
  int t = threadIdx.x;
  int base = kr*512;
  float v0 = ctx2T[(base + t      )*NB + b];
  float v1 = ctx2T[(base + 256 + t)*NB + b];
  float s = v0+v1, ss = v0*v0 + v1*v1, d0=0.f, d1=0.f;
  block_reduce4(s, ss, d0, d1);
  float m   = s * (1.0f/512.0f);
  float inv = rsqrtf((ss - s*m) * (1.0f/511.0f) + EPSF);
  modc[b*FFD + base + t      ] = (v0-m)*inv;
  modc[b*FFD + base + 256 + t] = (v1-m)*inv;
}

// scan pass: per-batch max_s/max_p + Sigma|v_s| partials. No plane stores.
__global__ __launch_bounds__(256) void k_scan(
    const float* __restrict__ modc,
    const float* __restrict__ convw, const float* __restrict__ convb,
    const float* __restrict__ wmod, const float* __restrict__ wstat,
    float* __restrict__ red, float* __restrict__ magpart){
  int b = blockIdx.x >> 4, chunk = blockIdx.x & 15;
  int t = threadIdx.x;
  __shared__ float lds[16*512];
  #pragma unroll
  for (int i = 0; i < 8; ++i){
    float4 v = *(const float4*)(modc + (size_t)b*FFD + (i*256 + t)*4);
    *(float4*)(lds + (i*256 + t)*4) = v;
  }
  float cw0 = convw[0]+convw[4]+convw[8]+convw[12];
  float cw1 = convw[1]+convw[5]+convw[9]+convw[13];
  float cw2 = convw[2]+convw[6]+convw[10]+convw[14];
  float cw3 = convw[3]+convw[7]+convw[11]+convw[15];
  float cb  = convb[0]+convb[1]+convb[2]+convb[3];
  __syncthreads();
  int w = t;
  float mxs = 0.f, mxp = 0.f, sas = 0.f;
  for (int it = 0; it < 16; ++it){
    int h = chunk*16 + it;
    int pix = h*WD + w;
    float r_, i_, p_, q_;
    pixel_core(lds, h, w, pix, cw0, cw1, cw2, cw3, cb, wmod, wstat,
               r_, i_, p_, q_);
    float as = sqrtf(r_*r_ + i_*i_ + EPSF);
    float ap = sqrtf(p_*p_ + q_*q_ + EPSF);
    mxs = fmaxf(mxs, as); mxp = fmaxf(mxp, ap);
    sas += as;
  }
  for (int off = 32; off > 0; off >>= 1){
    mxs = fmaxf(mxs, __shfl_down(mxs, off));
    mxp = fmaxf(mxp, __shfl_down(mxp, off));
    sas += __shfl_down(sas, off);
  }
  __shared__ float lred[12];
  int wid = t >> 6, lane = t & 63;
  if (lane == 0){ lred[wid] = mxs; lred[4+wid] = mxp; lred[8+wid] = sas; }
  __syncthreads();
  if (t == 0){
    float a = fmaxf(fmaxf(lred[0],lred[1]), fmaxf(lred[2],lred[3]));
    float p = fmaxf(fmaxf(lred[4],lred[5]), fmaxf(lred[6],lred[7]));
    float s = (lred[8]+lred[9])+(lred[10]+lred[11]);
    atomicMax((int*)&red[b],    __float_as_int(a));
    atomicMax((int*)&red[32+b], __float_as_int(p));
    magpart[b*16 + chunk] = s;
  }
}

// final: recompute pixels, combine with per-batch stats -> out
__global__ __launch_bounds__(256) void k_final(
    const float* __restrict__ modc,
    const float* __restrict__ convw, const float* __restrict__ convb,
    const float* __restrict__ wmod, const float* __restrict__ wstat,
    const float* __restrict__ red, const float* __restrict__ magpart,
    float* __restrict__ out){
  int b = blockIdx.x >> 4, chunk = blockIdx.x & 15;
  int t = threadIdx.x;
  __shared__ float lds[16*512];
  __shared__ float s_im;
  if (t < 16){
    float v = magpart[b*16 + t];
    for (int off = 8; off > 0; off >>= 1) v += __shfl_down(v, off);
    if (t == 0){
      float maxs = red[b];
      s_im = rsqrtf(v*(1.0f/65536.0f)/(maxs + EPSF) + EPSF);
    }
  }
  #pragma unroll
  for (int i = 0; i < 8; ++i){
    float4 v = *(const float4*)(modc + (size_t)b*FFD + (i*256 + t)*4);
    *(float4*)(lds + (i*256 + t)*4) = v;
  }
  float cw0 = convw[0]+convw[4]+convw[8]+convw[12];
  float cw1 = convw[1]+convw[5]+convw[9]+convw[13];
  float cw2 = convw[2]+convw[6]+convw[10]+convw[14];
  float cw3 = convw[3]+convw[7]+convw[11]+convw[15];
  float cb  = convb[0]+convb[1]+convb[2]+convb[3];
  __syncthreads();
  float im = s_im;
  float maxs = red[b], maxp = red[32+b];
  int w = t;
  for (int it = 0; it < 16; ++it){
    int h = chunk*16 + it;
    int pix = h*WD + w;
    float r_, i_, p_, q_;
    pixel_core(lds, h, w, pix, cw0, cw1, cw2, cw3, cb, wmod, wstat,
               r_, i_, p_, q_);
    float as = sqrtf(r_*r_ + i_*i_ + EPSF);
    float fs = (as/(maxs+EPSF))/(as+EPSF)*im;
    float2 A0 = *(const float2*)(wstat + (size_t)pix*2);
    float mwr = A0.x + fs*r_;
    float mwi = A0.y + fs*i_;
    float ap = sqrtf(p_*p_ + q_*q_ + EPSF);
    float fp = (ap/(maxp+EPSF))/(ap+EPSF);
    float mpr = fp*p_, mpi = fp*q_;
    float den = sqrtf(mpr*mpr + mpi*mpi + EPSF);
    out[(size_t)b*NPIX + pix] = (mwr*mpr + mwi*mpi)/den;
  }
}

// ---------- launch ----------

extern "C" void kernel_launch(void* const* d_in, const int* in_sizes, int n_in,
                              void* d_out, int out_size, void* d_ws, size_t ws_size,
                              hipStream_t stream){
  const float* x     = (const float*)d_in[0];
  const float* Win   = (const float*)d_in[1];
  const float* bin   = (const float*)d_in[2];
  const float* Wg    = (const float*)d_in[3];
  const float* bg    = (const float*)d_in[4];
  const float* Wt    = (const float*)d_in[5];
  const float* bt    = (const float*)d_in[6];
  const float* convw = (const float*)d_in[7];
  const float* convb = (const float*)d_in[8];
  const float* wstat = (const float*)d_in[9];
  const float* wmod  = (const float*)d_in[10];
  float* out = (float*)d_out;
  float* ws  = (float*)d_ws;

  // layout (floats); aliases are lifetime-disjoint:
  float* xtT   = ws;                       // dead after normgate
  float* xgT   = ws + 262144;              // dead after normgate
  float* ctx2T = ws;                       // alias xtT
  float* modc  = ws + 262144;              // alias xgT
  unsigned short* P2 = (unsigned short*)(ws + 524288);   // ctx pack, 256x2048 sh
  float* Cp    = ws + 966656;              // up to 16 x FFD*32 = 4.2M floats
  float* red     = ws + 9355264;           // max_s[32], max_p[32]
  float* magpart = ws + 9355328;           // [32][16]

  // GEMM1: K=1024, grid (f=64, kc=4, z=2), kslice=256; packs x in-kernel,
  // zeroes red[] from block 0
  k_gemm<8,true><<<dim3(64,4,2), 256, 0, stream>>>(Win, Wg, nullptr, x,
                                                   Cp, red, CTXD, 4ull*FFD*32);
  k_reduce1<<<2048, 256, 0, stream>>>(Cp, bin, bg, xtT, xgT);
  k_normgate<<<128, 256, 0, stream>>>(xtT, xgT, P2);
  // GEMM2: K=8192, grid (f=64, kc=16), kslice=512 (B restaged at s==8)
  k_gemm<16,false><<<dim3(64,16,1), 256, 0, stream>>>(Wt, Wt, P2, nullptr,
                                                      Cp, red, FFD, 0);
  k_reduce2<<<1024, 256, 0, stream>>>(Cp, bt, ctx2T);
  k_norm512<<<512, 256, 0, stream>>>(ctx2T, modc);
  k_scan<<<512, 256, 0, stream>>>(modc, convw, convb, wmod, wstat, red, magpart);
  k_final<<<512, 256, 0, stream>>>(modc, convw, convb, wmod, wstat, red,
                                   magpart, out);
}

// Round 16
// 151.992 us; speedup vs baseline: 1.1912x; 1.0017x over previous
//
#include <hip/hip_runtime.h>
#include <cstddef>

#define NB   32
#define CTXD 1024
#define FFD  8192
#define HD   256
#define WD   256
#define NPIX 65536
#define EPSF 1e-12f
#define SCF  4096.0f
#define ISCF (1.0f/4096.0f)

typedef __attribute__((ext_vector_type(8))) _Float16 half8;
typedef __attribute__((ext_vector_type(4))) float f32x4;

// ---------- helpers ----------

__device__ __forceinline__ float ftanh(float x){
  float ax = fabsf(x);
  float e  = __expf(2.0f*ax);
  float r  = 1.0f - 2.0f*__builtin_amdgcn_rcpf(e + 1.0f);
  return copysignf(r, x);
}

// split f32 -> 2 f16 terms: f ~= h0 + h1*2^-12 (residual ~2^-22 relative)
__device__ __forceinline__ void split2h(float f, _Float16& h0, _Float16& h1){
  h0 = (_Float16)f;
  float r = (f - (float)h0) * SCF;
  h1 = (_Float16)r;
}

// async global->LDS: lane L's 16B lands at l + L*16; global src per-lane
__device__ __forceinline__ void gload_lds16(const void* g, void* l){
  __builtin_amdgcn_global_load_lds(
      (__attribute__((address_space(1))) void*)g,
      (__attribute__((address_space(3))) void*)l, 16, 0, 0);
}

__device__ __forceinline__ void block_reduce4(float& a, float& b, float& c, float& d){
  for (int off = 32; off > 0; off >>= 1){
    a += __shfl_down(a, off); b += __shfl_down(b, off);
    c += __shfl_down(c, off); d += __shfl_down(d, off);
  }
  __shared__ float lds[16];
  int wid = threadIdx.x >> 6, lane = threadIdx.x & 63;
  if (lane == 0){ lds[wid*4+0]=a; lds[wid*4+1]=b; lds[wid*4+2]=c; lds[wid*4+3]=d; }
  __syncthreads();
  a = (lds[0]+lds[4])+(lds[8]+lds[12]);
  b = (lds[1]+lds[5])+(lds[9]+lds[13]);
  c = (lds[2]+lds[6])+(lds[10]+lds[14]);
  d = (lds[3]+lds[7])+(lds[11]+lds[15]);
}

// per-pixel recompute core shared by k_scan / k_final (must stay identical)
__device__ __forceinline__ void pixel_core(
    const float* __restrict__ lds, int h, int w, int pix,
    float cw0, float cw1, float cw2, float cw3, float cb,
    const float* __restrict__ wmod, const float* __restrict__ wstat,
    float& r_, float& i_, float& p_, float& q_){
  float sk[4];
  #pragma unroll
  for (int k = 0; k < 4; ++k){
    float acc = 0.f;
    #pragma unroll
    for (int r = 0; r < 4; ++r){
      int kr = k*4 + r;
      float u  = lds[kr*512 + h];
      float vv = lds[kr*512 + 256 + w];
      float tt = ftanh(u*vv);
      float cwr = (r==0)?cw0:(r==1)?cw1:(r==2)?cw2:cw3;
      acc += (k==0) ? cwr*tt : tt;
    }
    sk[k] = acc;
  }
  sk[0] += cb;
  float m0 = sk[0]*wmod[0*NPIX+pix];
  float m1 = sk[1]*wmod[1*NPIX+pix];
  float m2 = sk[2]*wmod[2*NPIX+pix];
  float m3 = sk[3]*wmod[3*NPIX+pix];
  float2 A1 = *(const float2*)(wstat + (size_t)(NPIX + pix)*2);
  r_ = A1.x*m0 - A1.y*m1;
  i_ = A1.x*m1 - A1.y*m0;
  p_ = m2; q_ = m3;
}

// ---------- kernels ----------

// B-reuse streaming 2xf16-split MFMA GEMM.
// Block = 4 waves x 128 features x kslice STEPS*32.
// PACKB=true  (GEMM1): B built in-kernel from f32 X slice; zeroes red[].
// PACKB=false (GEMM2): B staged from the packed ctx buffer in 8-chunk
//                      groups, restaged every 8 steps (barrier-converged).
// W staged per-step (128x32k, dbuf, per-wave-owned quarter, no in-loop
// barriers except restage points). result = accH + accL/4096.
template<int STEPS, bool PACKB>
__global__ __launch_bounds__(256) void k_gemm(
    const float* __restrict__ W0, const float* __restrict__ W1,
    const unsigned short* __restrict__ BP, const float* __restrict__ X,
    float* __restrict__ Cp, float* __restrict__ red, int K, size_t zstride){
  __shared__ float wtile[2][4096];           // 2 x (128 rows x 32 k) = 32KB
  __shared__ unsigned short bpack[16384];    // 8 chunks x 2048 = 32KB
  const int t = threadIdx.x;
  const int wv = t >> 6, lane = t & 63;
  const int row = lane & 15, kg = lane >> 4;
  const int f0 = blockIdx.x * 128;
  const int kc = blockIdx.y;
  const float* __restrict__ W = blockIdx.z ? W1 : W0;
  const int kb = kc * (STEPS*32);

  if (PACKB && blockIdx.x == 0 && blockIdx.y == 0 && blockIdx.z == 0 && t < 64)
    red[t] = 0.0f;

  if constexpr (PACKB){
    // build B pack from f32 X slice: 1024 units (32 b x 32 8k-groups)
    for (int u = t; u < 1024; u += 256){
      int b = u >> 5, grp = u & 31;
      const float* src = X + (size_t)b*K + kb + grp*8;
      float4 v0 = *(const float4*)(src), v1 = *(const float4*)(src+4);
      float vv[8] = {v0.x,v0.y,v0.z,v0.w,v1.x,v1.y,v1.z,v1.w};
      half8 g0, g1;
      #pragma unroll
      for (int e = 0; e < 8; ++e){
        _Float16 h0,h1; split2h(vv[e],h0,h1);
        g0[e]=h0; g1[e]=h1;
      }
      int c = grp >> 2, kgp = grp & 3;
      size_t base = (size_t)c*2048 + (b>>4)*512 + kgp*128 + (b&15)*8;
      *(half8*)(bpack + base)        = g0;
      *(half8*)(bpack + base + 1024) = g1;
    }
  } else {
    const unsigned short* bsrc = BP + (size_t)(kc*STEPS)*2048;
    #pragma unroll
    for (int i = 0; i < 8; ++i){
      int call = wv*8 + i;
      gload_lds16(bsrc + call*512 + lane*8, bpack + call*512);
    }
  }
  // W stage for step s into wtile[buf]; wave stages its own 32 rows as
  // 4 x 1KB calls (8 rows x 128B each). Source piece XOR-swizzled (T21).
  auto stageW = [&](int buf, int s){
    const int kbase = kb + s*32;
    #pragma unroll
    for (int i = 0; i < 4; ++i){
      int call = wv*4 + i;
      const float* src = W + (size_t)(f0 + call*8 + (lane>>3))*K + kbase
                           + (((lane&7) ^ ((lane>>3)&7)) << 2);
      gload_lds16(src, &wtile[buf][call*256]);
    }
  };

  stageW(0, 0);
  asm volatile("s_waitcnt vmcnt(0)" ::: "memory");
  __syncthreads();                            // B(+pack writes) + W0 visible

  f32x4 aH0l={0.f,0.f,0.f,0.f}, aH0h={0.f,0.f,0.f,0.f};
  f32x4 aL0l={0.f,0.f,0.f,0.f}, aL0h={0.f,0.f,0.f,0.f};
  f32x4 aH1l={0.f,0.f,0.f,0.f}, aH1h={0.f,0.f,0.f,0.f};
  f32x4 aL1l={0.f,0.f,0.f,0.f}, aL1h={0.f,0.f,0.f,0.f};
  int cur = 0;
  const int sw = row & 7;

  for (int s = 0; s < STEPS; ++s){
    if constexpr (!PACKB && STEPS > 8){
      if (s && (s & 7) == 0){
        __syncthreads();                      // all waves done with prev 8
        const unsigned short* bsrc = BP + (size_t)(kc*STEPS + s)*2048;
        #pragma unroll
        for (int i = 0; i < 8; ++i){
          int call = wv*8 + i;
          gload_lds16(bsrc + call*512 + lane*8, bpack + call*512);
        }
      }
    }
    if (s + 1 < STEPS) stageW(cur ^ 1, s + 1);
    // wait: everything older than stage(s+1)'s 4 ops is drained
    asm volatile("s_waitcnt vmcnt(4)" ::: "memory");
    __builtin_amdgcn_sched_barrier(0);
    const unsigned short* bch = bpack + (size_t)(s & 7)*2048 + kg*128 + row*8;
    half8 b0l = *(const half8*)(bch);          // plane0, batches 0..15
    half8 b0h = *(const half8*)(bch +  512);   // plane0, batches 16..31
    half8 b1l = *(const half8*)(bch + 1024);   // plane1 (x4096)
    half8 b1h = *(const half8*)(bch + 1536);
    #pragma unroll
    for (int T = 0; T < 2; ++T){
      const float* wr = &wtile[cur][(wv*32 + T*16 + row)*32];
      float4 lo = *(const float4*)(wr + (((2*kg  ) ^ sw) << 2));
      float4 hi = *(const float4*)(wr + (((2*kg+1) ^ sw) << 2));
      half8 a0, a1;
      float wv8[8] = {lo.x,lo.y,lo.z,lo.w,hi.x,hi.y,hi.z,hi.w};
      #pragma unroll
      for (int e = 0; e < 8; ++e){
        _Float16 h0,h1; split2h(wv8[e],h0,h1);
        a0[e]=h0; a1[e]=h1;
      }
      if (T == 0){
        aH0l = __builtin_amdgcn_mfma_f32_16x16x32_f16(a0, b0l, aH0l, 0,0,0);
        aH0h = __builtin_amdgcn_mfma_f32_16x16x32_f16(a0, b0h, aH0h, 0,0,0);
        aL0l = __builtin_amdgcn_mfma_f32_16x16x32_f16(a0, b1l, aL0l, 0,0,0);
        aL0h = __builtin_amdgcn_mfma_f32_16x16x32_f16(a0, b1h, aL0h, 0,0,0);
        aL0l = __builtin_amdgcn_mfma_f32_16x16x32_f16(a1, b0l, aL0l, 0,0,0);
        aL0h = __builtin_amdgcn_mfma_f32_16x16x32_f16(a1, b0h, aL0h, 0,0,0);
      } else {
        aH1l = __builtin_amdgcn_mfma_f32_16x16x32_f16(a0, b0l, aH1l, 0,0,0);
        aH1h = __builtin_amdgcn_mfma_f32_16x16x32_f16(a0, b0h, aH1h, 0,0,0);
        aL1l = __builtin_amdgcn_mfma_f32_16x16x32_f16(a0, b1l, aL1l, 0,0,0);
        aL1h = __builtin_amdgcn_mfma_f32_16x16x32_f16(a0, b1h, aL1h, 0,0,0);
        aL1l = __builtin_amdgcn_mfma_f32_16x16x32_f16(a1, b0l, aL1l, 0,0,0);
        aL1h = __builtin_amdgcn_mfma_f32_16x16x32_f16(a1, b0h, aL1h, 0,0,0);
      }
    }
    cur ^= 1;
  }

  float* __restrict__ C = Cp + (size_t)blockIdx.z*zstride + (size_t)kc*(FFD*32);
  #pragma unroll
  for (int r = 0; r < 4; ++r){               // C/D: col=lane&15, row=kg*4+r
    int fA = f0 + wv*32 + kg*4 + r;
    int fB = fA + 16;
    C[(size_t)fA*32 + row]      = aH0l[r] + aL0l[r]*ISCF;
    C[(size_t)fA*32 + 16 + row] = aH0h[r] + aL0h[r]*ISCF;
    C[(size_t)fB*32 + row]      = aH1l[r] + aL1l[r]*ISCF;
    C[(size_t)fB*32 + 16 + row] = aH1h[r] + aL1h[r]*ISCF;
  }
}

// reduce for GEMM1 (both matrices), S=4 — coalesced (g-contiguous)
__global__ __launch_bounds__(256) void k_reduce1(
    const float* __restrict__ Cp, const float* __restrict__ bin,
    const float* __restrict__ bg, float* __restrict__ xtT,
    float* __restrict__ xgT){
  int g = blockIdx.x*256 + threadIdx.x;          // 524288
  int m = g >> 18, idx = g & 262143;
  int f = idx >> 5;
  const float* __restrict__ cp = Cp + (size_t)m*(4ull*FFD*32);
  float s = (m ? bg : bin)[f];
  #pragma unroll
  for (int sI = 0; sI < 4; ++sI) s += cp[(size_t)sI*(FFD*32) + idx];
  (m ? xgT : xtT)[idx] = s;
}

// reduce for GEMM2, S=8 — coalesced (g-contiguous)
__global__ __launch_bounds__(256) void k_reduce2(
    const float* __restrict__ Cp, const float* __restrict__ bias,
    float* __restrict__ outT){
  int g = blockIdx.x*256 + threadIdx.x;          // 262144
  int f = g >> 5;
  float s = bias[f];
  #pragma unroll
  for (int sI = 0; sI < 8; ++sI) s += Cp[(size_t)sI*(FFD*32) + g];
  outT[g] = s;
}

// norm over 2048-groups (ddof=1); ctx = nt*tanh(ng) -> packed f16 2-plane
__global__ __launch_bounds__(256) void k_normgate(
    const float* __restrict__ xtT, const float* __restrict__ xgT,
    unsigned short* __restrict__ P){
  int b = blockIdx.x >> 2, g4 = blockIdx.x & 3;
  int t = threadIdx.x;
  int f8 = g4*2048 + t*8;
  float vt[8], vg[8];
  float st=0.f, sst=0.f, sg=0.f, ssg=0.f;
  #pragma unroll
  for (int i = 0; i < 8; ++i){
    int f = f8 + i;
    float a = xtT[(size_t)f*NB + b];
    float c = xgT[(size_t)f*NB + b];
    vt[i]=a; vg[i]=c;
    st += a; sst += a*a; sg += c; ssg += c*c;
  }
  block_reduce4(st, sst, sg, ssg);
  float mt = st * (1.0f/2048.0f);
  float it = rsqrtf((sst - st*mt) * (1.0f/2047.0f) + EPSF);
  float mg = sg * (1.0f/2048.0f);
  float ig = rsqrtf((ssg - sg*mg) * (1.0f/2047.0f) + EPSF);
  half8 g0, g1;
  #pragma unroll
  for (int i = 0; i < 8; ++i){
    float nt = (vt[i]-mt)*it;
    float ng = (vg[i]-mg)*ig;
    float cv = nt * ftanh(ng);
    _Float16 h0,h1; split2h(cv,h0,h1);
    g0[i]=h0; g1[i]=h1;
  }
  int c2 = f8 >> 5, kg = (f8 >> 3) & 3;
  size_t base = (size_t)c2*2048 + (b>>4)*512 + kg*128 + (b&15)*8;
  *(half8*)(P + base)        = g0;
  *(half8*)(P + base + 1024) = g1;
}

// norm over 512-groups (ddof=1) -> modc [B][16][512]
__global__ __launch_bounds__(256) void k_norm512(
    const float* __restrict__ ctx2T, float* __restrict__ modc){
  int b = blockIdx.x >> 4, kr = blockIdx.x & 15;
  int t = threadIdx.x;
  int base = kr*512;
  float v0 = ctx2T[(base + t      )*NB + b];
  float v1 = ctx2T[(base + 256 + t)*NB + b];
  float s = v0+v1, ss = v0*v0 + v1*v1, d0=0.f, d1=0.f;
  block_reduce4(s, ss, d0, d1);
  float m   = s * (1.0f/512.0f);
  float inv = rsqrtf((ss - s*m) * (1.0f/511.0f) + EPSF);
  modc[b*FFD + base + t      ] = (v0-m)*inv;
  modc[b*FFD + base + 256 + t] = (v1-m)*inv;
}

// scan pass: per-batch max_s/max_p + Sigma|v_s| partials. No plane stores.
__global__ __launch_bounds__(256) void k_scan(
    const float* __restrict__ modc,
    const float* __restrict__ convw, const float* __restrict__ convb,
    const float* __restrict__ wmod, const float* __restrict__ wstat,
    float* __restrict__ red, float* __restrict__ magpart){
  int b = blockIdx.x >> 4, chunk = blockIdx.x & 15;
  int t = threadIdx.x;
  __shared__ float lds[16*512];
  #pragma unroll
  for (int i = 0; i < 8; ++i){
    float4 v = *(const float4*)(modc + (size_t)b*FFD + (i*256 + t)*4);
    *(float4*)(lds + (i*256 + t)*4) = v;
  }
  float cw0 = convw[0]+convw[4]+convw[8]+convw[12];
  float cw1 = convw[1]+convw[5]+convw[9]+convw[13];
  float cw2 = convw[2]+convw[6]+convw[10]+convw[14];
  float cw3 = convw[3]+convw[7]+convw[11]+convw[15];
  float cb  = convb[0]+convb[1]+convb[2]+convb[3];
  __syncthreads();
  int w = t;
  float mxs = 0.f, mxp = 0.f, sas = 0.f;
  for (int it = 0; it < 16; ++it){
    int h = chunk*16 + it;
    int pix = h*WD + w;
    float r_, i_, p_, q_;
    pixel_core(lds, h, w, pix, cw0, cw1, cw2, cw3, cb, wmod, wstat,
               r_, i_, p_, q_);
    float as = sqrtf(r_*r_ + i_*i_ + EPSF);
    float ap = sqrtf(p_*p_ + q_*q_ + EPSF);
    mxs = fmaxf(mxs, as); mxp = fmaxf(mxp, ap);
    sas += as;
  }
  for (int off = 32; off > 0; off >>= 1){
    mxs = fmaxf(mxs, __shfl_down(mxs, off));
    mxp = fmaxf(mxp, __shfl_down(mxp, off));
    sas += __shfl_down(sas, off);
  }
  __shared__ float lred[12];
  int wid = t >> 6, lane = t & 63;
  if (lane == 0){ lred[wid] = mxs; lred[4+wid] = mxp; lred[8+wid] = sas; }
  __syncthreads();
  if (t == 0){
    float a = fmaxf(fmaxf(lred[0],lred[1]), fmaxf(lred[2],lred[3]));
    float p = fmaxf(fmaxf(lred[4],lred[5]), fmaxf(lred[6],lred[7]));
    float s = (lred[8]+lred[9])+(lred[10]+lred[11]);
    atomicMax((int*)&red[b],    __float_as_int(a));
    atomicMax((int*)&red[32+b], __float_as_int(p));
    magpart[b*16 + chunk] = s;
  }
}

// final: recompute pixels, combine with per-batch stats -> out
__global__ __launch_bounds__(256) void k_final(
    const float* __restrict__ modc,
    const float* __restrict__ convw, const float* __restrict__ convb,
    const float* __restrict__ wmod, const float* __restrict__ wstat,
    const float* __restrict__ red, const float* __restrict__ magpart,
    float* __restrict__ out){
  int b = blockIdx.x >> 4, chunk = blockIdx.x & 15;
  int t = threadIdx.x;
  __shared__ float lds[16*512];
  __shared__ float s_im;
  if (t < 16){
    float v = magpart[b*16 + t];
    for (int off = 8; off > 0; off >>= 1) v += __shfl_down(v, off);
    if (t == 0){
      float maxs = red[b];
      s_im = rsqrtf(v*(1.0f/65536.0f)/(maxs + EPSF) + EPSF);
    }
  }
  #pragma unroll
  for (int i = 0; i < 8; ++i){
    float4 v = *(const float4*)(modc + (size_t)b*FFD + (i*256 + t)*4);
    *(float4*)(lds + (i*256 + t)*4) = v;
  }
  float cw0 = convw[0]+convw[4]+convw[8]+convw[12];
  float cw1 = convw[1]+convw[5]+convw[9]+convw[13];
  float cw2 = convw[2]+convw[6]+convw[10]+convw[14];
  float cw3 = convw[3]+convw[7]+convw[11]+convw[15];
  float cb  = convb[0]+convb[1]+convb[2]+convb[3];
  __syncthreads();
  float im = s_im;
  float maxs = red[b], maxp = red[32+b];
  int w = t;
  for (int it = 0; it < 16; ++it){
    int h = chunk*16 + it;
    int pix = h*WD + w;
    float r_, i_, p_, q_;
    pixel_core(lds, h, w, pix, cw0, cw1, cw2, cw3, cb, wmod, wstat,
               r_, i_, p_, q_);
    float as = sqrtf(r_*r_ + i_*i_ + EPSF);
    float fs = (as/(maxs+EPSF))/(as+EPSF)*im;
    float2 A0 = *(const float2*)(wstat + (size_t)pix*2);
    float mwr = A0.x + fs*r_;
    float mwi = A0.y + fs*i_;
    float ap = sqrtf(p_*p_ + q_*q_ + EPSF);
    float fp = (ap/(maxp+EPSF))/(ap+EPSF);
    float mpr = fp*p_, mpi = fp*q_;
    float den = sqrtf(mpr*mpr + mpi*mpi + EPSF);
    out[(size_t)b*NPIX + pix] = (mwr*mpr + mwi*mpi)/den;
  }
}

// ---------- launch ----------

extern "C" void kernel_launch(void* const* d_in, const int* in_sizes, int n_in,
                              void* d_out, int out_size, void* d_ws, size_t ws_size,
                              hipStream_t stream){
  const float* x     = (const float*)d_in[0];
  const float* Win   = (const float*)d_in[1];
  const float* bin   = (const float*)d_in[2];
  const float* Wg    = (const float*)d_in[3];
  const float* bg    = (const float*)d_in[4];
  const float* Wt    = (const float*)d_in[5];
  const float* bt    = (const float*)d_in[6];
  const float* convw = (const float*)d_in[7];
  const float* convb = (const float*)d_in[8];
  const float* wstat = (const float*)d_in[9];
  const float* wmod  = (const float*)d_in[10];
  float* out = (float*)d_out;
  float* ws  = (float*)d_ws;

  // layout (floats); aliases are lifetime-disjoint:
  float* xtT   = ws;                       // dead after normgate
  float* xgT   = ws + 262144;              // dead after normgate
  float* ctx2T = ws;                       // alias xtT
  float* modc  = ws + 262144;              // alias xgT
  unsigned short* P2 = (unsigned short*)(ws + 524288);   // ctx pack, 256x2048 sh
  float* Cp    = ws + 966656;              // up to 8 x FFD*32 = 2.1M floats
  float* red     = ws + 9355264;           // max_s[32], max_p[32]
  float* magpart = ws + 9355328;           // [32][16]

  // GEMM1: K=1024, grid (f=64, kc=4, z=2), kslice=256; packs x in-kernel,
  // zeroes red[] from block 0
  k_gemm<8,true><<<dim3(64,4,2), 256, 0, stream>>>(Win, Wg, nullptr, x,
                                                   Cp, red, CTXD, 4ull*FFD*32);
  k_reduce1<<<2048, 256, 0, stream>>>(Cp, bin, bg, xtT, xgT);
  k_normgate<<<128, 256, 0, stream>>>(xtT, xgT, P2);
  // GEMM2: K=8192, grid (f=64, kc=8), kslice=1024 (B restaged at s=8,16,24)
  k_gemm<32,false><<<dim3(64,8,1), 256, 0, stream>>>(Wt, Wt, P2, nullptr,
                                                     Cp, red, FFD, 0);
  k_reduce2<<<1024, 256, 0, stream>>>(Cp, bt, ctx2T);
  k_norm512<<<512, 256, 0, stream>>>(ctx2T, modc);
  k_scan<<<512, 256, 0, stream>>>(modc, convw, convb, wmod, wstat, red, magpart);
  k_final<<<512, 256, 0, stream>>>(modc, convw, convb, wmod, wstat, red,
                                   magpart, out);
}